// Round 6
// baseline (551.030 us; speedup 1.0000x reference)
//
#include <hip/hip_runtime.h>
#include <hip/hip_bf16.h>
#include <math.h>

// q [8192,1024] f32, k [8192,1024] f32, v [8192,1024] f32
// scores = q@k^T; x = scores/||row|| * sqrt(8192); gated = gelu_exact(x); out = gated@v
//
// ws layout (~176 MiB):
//   [0,16M)    qb   bf16 8192x1024
//   [16M,32M)  kb   bf16 8192x1024
//   [32M,48M)  vbT  bf16 1024x8192
//   [48M,176M) scores/gated bf16 8192x8192 (in-place gelu)
//   [176M,+32K) sumsq f32 [8192]
//
// GEMM1 (this round): 128x256 tile, 8 waves of 64x64 (acc=64 regs ->
// launch_bounds(512,4) -> 2 blocks/CU), BK=32, 3-buffer ring with depth-2
// prefetch + counted vmcnt(3), ONE barrier per K-step. Mechanism: cross-block
// TLP hides the ~3000cy/K-tile of barrier/wait bubbles R5 exposed at 1 blk/CU.
// Both-sides XOR slot swizzle kept (R5: conflicts == 0, verified).

#define MROWS 8192
#define DIN   1024
#define NBANK 8192
#define DOUT  1024

typedef float  f32x4  __attribute__((ext_vector_type(4)));
typedef __bf16 bf16x8 __attribute__((ext_vector_type(8)));

__device__ __forceinline__ float bf2f(unsigned short u) {
  union { unsigned int i; float f; } x; x.i = ((unsigned int)u) << 16; return x.f;
}
__device__ __forceinline__ unsigned short f2bf(float f) {
  union { float f; unsigned int i; } x; x.f = f;
  unsigned int u = x.i;
  unsigned int r = (u + 0x7fffu + ((u >> 16) & 1u)) >> 16;  // RNE
  return (unsigned short)r;
}

// ---------------- fp32 -> bf16 convert ----------------
__global__ void cvt_kernel(const float* __restrict__ src,
                           unsigned short* __restrict__ dst, int n) {
  int i = (blockIdx.x * 256 + threadIdx.x) * 4;
  if (i >= n) return;
  float4 vv = *(const float4*)(src + i);
  ushort4 o;
  o.x = f2bf(vv.x); o.y = f2bf(vv.y); o.z = f2bf(vv.z); o.w = f2bf(vv.w);
  *(ushort4*)(dst + i) = o;
}

// ---------------- transpose + convert: src[R][C] f32 -> dst[C][R] bf16 ----------------
__global__ void transpose_cvt_kernel(const float* __restrict__ src,
                                     unsigned short* __restrict__ dst,
                                     int R, int C) {
  __shared__ float tile[32][33];
  int c0 = blockIdx.x * 32, r0 = blockIdx.y * 32;
  for (int i = threadIdx.y; i < 32; i += 8)
    tile[i][threadIdx.x] = src[(size_t)(r0 + i) * C + c0 + threadIdx.x];
  __syncthreads();
  for (int i = threadIdx.y; i < 32; i += 8)
    dst[(size_t)(c0 + i) * R + r0 + threadIdx.x] = f2bf(tile[threadIdx.x][i]);
}

// ---------------- zero fill (float4 granularity) ----------------
__global__ void zero_f32_kernel(float* __restrict__ p, int n4) {
  int i = blockIdx.x * 256 + threadIdx.x;
  if (i < n4) ((float4*)p)[i] = make_float4(0.f, 0.f, 0.f, 0.f);
}

// ---------------- GEMM1: scores = qb @ kb^T (bf16 out) + row sumsq atomics ----------
// Tile 128x256, 512 thr = 8 waves (2M x 4N) of 64x64. BK=32, 3-buf ring.
// LDS: A 3x[128][32] = 24 KiB, B 3x[256][32] = 48 KiB -> 72 KiB -> 2 blocks/CU.
__global__ __launch_bounds__(512, 4) void gemm1_kernel(
    const unsigned short* __restrict__ A, const unsigned short* __restrict__ B,
    unsigned short* __restrict__ C, float* __restrict__ sumsq) {
  __shared__ unsigned short As[3 * 4096];
  __shared__ unsigned short Bs[3 * 8192];
  const int K = DIN;
  const int NKT = DIN / 32;  // 32 K-steps

  const int tid  = threadIdx.x;
  const int lane = tid & 63;
  const int wm   = (tid >> 6) >> 2;  // 0..1  (64-row group)
  const int wn   = (tid >> 6) & 3;   // 0..3  (64-col group)
  const int quad = lane >> 4;
  const int l16  = lane & 15;

  // XCD-aware bijective swizzle: nwg = 32*64 = 2048, %8==0.
  const int flat = blockIdx.y * gridDim.x + blockIdx.x;
  const int nwg  = gridDim.x * gridDim.y;
  const int swz  = (flat & 7) * (nwg >> 3) + (flat >> 3);
  const size_t m0 = (size_t)(swz / gridDim.x) * 128;
  const size_t n0 = (size_t)(swz % gridDim.x) * 256;

  // read-side swizzle: 16B slot = quad ^ ((row>>1)&3); all frag-row strides
  // (16, 64) are multiples of 8 so the XOR depends only on l16.
  const int sw   = (l16 >> 1) & 3;
  const int aoff = (wm * 64 + l16) * 32 + (quad ^ sw) * 8;
  const int boff = (wn * 64 + l16) * 32 + (quad ^ sw) * 8;

  // source-side swizzle: thread (row=tid>>2, slot=tid&3) fetches global slot
  // (tid&3) ^ ((row>>1)&3); row offsets +128 preserve (row>>1)&3.
  const int gslot = (tid & 3) ^ ((tid >> 3) & 3);
  const unsigned short* Ag = A + (m0 + (tid >> 2)) * (size_t)K + gslot * 8;
  const unsigned short* Bg = B + (n0 + (tid >> 2)) * (size_t)K + gslot * 8;

  f32x4 acc[4][4];
#pragma unroll
  for (int i = 0; i < 4; i++)
#pragma unroll
    for (int j = 0; j < 4; j++) {
      f32x4 z = {0.f, 0.f, 0.f, 0.f};
      acc[i][j] = z;
    }

  // stage one K-step into ring buffer `buf` (3 gload_lds / thread)
  auto stage = [&](int buf, int koff) {
    __builtin_amdgcn_global_load_lds(
        (const __attribute__((address_space(1))) unsigned int*)(Ag + koff),
        (__attribute__((address_space(3))) unsigned int*)(As + buf * 4096 + tid * 8),
        16, 0, 0);
    __builtin_amdgcn_global_load_lds(
        (const __attribute__((address_space(1))) unsigned int*)(Bg + koff),
        (__attribute__((address_space(3))) unsigned int*)(Bs + buf * 8192 + tid * 8),
        16, 0, 0);
    __builtin_amdgcn_global_load_lds(
        (const __attribute__((address_space(1))) unsigned int*)(Bg + (size_t)128 * K +
                                                                koff),
        (__attribute__((address_space(3))) unsigned int*)(Bs + buf * 8192 + 4096 +
                                                          tid * 8),
        16, 0, 0);
  };

  // prologue: depth-2 prefetch
  stage(0, 0);
  stage(1, 32);
  asm volatile("s_waitcnt vmcnt(3)" ::: "memory");  // buf0's 3 loads landed
  __builtin_amdgcn_s_barrier();
  __builtin_amdgcn_sched_barrier(0);

  int cur = 0;
  for (int t = 0; t < NKT; ++t) {
    const bool pf = (t + 2) < NKT;
    if (pf) {
      int nxt = cur + 2;
      if (nxt >= 3) nxt -= 3;
      stage(nxt, (t + 2) * 32);
    }

    const unsigned short* Ab = As + cur * 4096 + aoff;
    const unsigned short* Bb = Bs + cur * 8192 + boff;
    bf16x8 a[4], b[4];
#pragma unroll
    for (int i = 0; i < 4; ++i) a[i] = *(const bf16x8*)(Ab + i * 512);
#pragma unroll
    for (int j = 0; j < 4; ++j) b[j] = *(const bf16x8*)(Bb + j * 512);

    asm volatile("s_waitcnt lgkmcnt(0)" ::: "memory");
    __builtin_amdgcn_sched_barrier(0);
    __builtin_amdgcn_s_setprio(1);
#pragma unroll
    for (int i = 0; i < 4; ++i)
#pragma unroll
      for (int j = 0; j < 4; ++j)
        acc[i][j] = __builtin_amdgcn_mfma_f32_16x16x32_bf16(a[i], b[j], acc[i][j],
                                                            0, 0, 0);
    __builtin_amdgcn_s_setprio(0);

    // counted wait: keep the just-issued step in flight; next step must have landed
    if (pf)
      asm volatile("s_waitcnt vmcnt(3)" ::: "memory");
    else
      asm volatile("s_waitcnt vmcnt(0)" ::: "memory");
    __builtin_amdgcn_s_barrier();
    __builtin_amdgcn_sched_barrier(0);

    cur = (cur == 2) ? 0 : cur + 1;
  }

  // Epilogue: bf16 scores + per-row sumsq atomics
#pragma unroll
  for (int mf = 0; mf < 4; ++mf)
#pragma unroll
    for (int r = 0; r < 4; ++r) {
      size_t row = m0 + wm * 64 + mf * 16 + quad * 4 + r;
      float s = 0.f;
#pragma unroll
      for (int nf = 0; nf < 4; ++nf) {
        float val = acc[mf][nf][r];
        s += val * val;
        C[row * (size_t)NBANK + n0 + wn * 64 + nf * 16 + l16] = f2bf(val);
      }
      s += __shfl_xor(s, 1);
      s += __shfl_xor(s, 2);
      s += __shfl_xor(s, 4);
      s += __shfl_xor(s, 8);
      if (l16 == 0) atomicAdd(&sumsq[row], s);
    }
}

// ---------------- in-place exact GELU(x * sqrt(N/sumsq[row])) ----------------
__global__ void gelu_kernel(unsigned short* __restrict__ S,
                            const float* __restrict__ sumsq) {
  const size_t total = (size_t)MROWS * NBANK / 8;  // uint4 units
  for (size_t u = (size_t)blockIdx.x * 256 + threadIdx.x; u < total;
       u += (size_t)gridDim.x * 256) {
    size_t idx = u * 8;
    int row = (int)(idx >> 13);
    float sc = sqrtf((float)NBANK / sumsq[row]);
    uint4 vv = *(const uint4*)(S + idx);
    unsigned int w[4] = {vv.x, vv.y, vv.z, vv.w};
#pragma unroll
    for (int e = 0; e < 4; e++) {
      float x0 = bf2f((unsigned short)(w[e] & 0xffffu)) * sc;
      float x1 = bf2f((unsigned short)(w[e] >> 16)) * sc;
      float g0 = 0.5f * x0 * (1.0f + erff(x0 * 0.70710678118654752f));
      float g1 = 0.5f * x1 * (1.0f + erff(x1 * 0.70710678118654752f));
      w[e] = (unsigned int)f2bf(g0) | ((unsigned int)f2bf(g1) << 16);
    }
    uint4 o; o.x = w[0]; o.y = w[1]; o.z = w[2]; o.w = w[3];
    *(uint4*)(S + idx) = o;
  }
}

// ---------------- GEMM2: out = gated @ vbT^T, 128x128 tile, NO split-K --------------
// m97-class structure + both-sides LDS XOR swizzle (unchanged control arm).
__global__ __launch_bounds__(256, 4) void gemm2_kernel(
    const unsigned short* __restrict__ A,   // gated [8192][8192]
    const unsigned short* __restrict__ B,   // vbT   [1024][8192]
    float* __restrict__ C) {                // out   [8192][1024]
  __shared__ unsigned short As[128 * 32];
  __shared__ unsigned short Bs[128 * 32];
  const int K = NBANK, ldc = DOUT;

  const int tid  = threadIdx.x;
  const int lane = tid & 63;
  const int wave = tid >> 6;
  const int wm   = (wave >> 1) * 64;
  const int wn   = (wave & 1) * 64;
  const int quad = lane >> 4;
  const int l16  = lane & 15;

  // XCD swizzle: nwg = 8*64 = 512, %8==0.
  const int flat = blockIdx.y * gridDim.x + blockIdx.x;
  const int nwg  = gridDim.x * gridDim.y;
  const int swz  = (flat & 7) * (nwg >> 3) + (flat >> 3);
  const size_t m0 = (size_t)(swz / gridDim.x) * 128;
  const size_t n0 = (size_t)(swz % gridDim.x) * 128;

  const int srow = tid >> 2;
  const int scol = (((tid & 3) ^ ((tid >> 3) & 3))) * 8;
  const unsigned short* Ag0 = A + (m0 + srow) * (size_t)K + scol;
  const unsigned short* Ag1 = A + (m0 + srow + 64) * (size_t)K + scol;
  const unsigned short* Bg0 = B + (n0 + srow) * (size_t)K + scol;
  const unsigned short* Bg1 = B + (n0 + srow + 64) * (size_t)K + scol;

  unsigned short* AsW0 = As + tid * 8;
  unsigned short* AsW1 = As + 64 * 32 + tid * 8;
  unsigned short* BsW0 = Bs + tid * 8;
  unsigned short* BsW1 = Bs + 64 * 32 + tid * 8;

  const int sw = (l16 >> 1) & 3;
  const unsigned short* ArP = As + (wm + l16) * 32 + (quad ^ sw) * 8;
  const unsigned short* BrP = Bs + (wn + l16) * 32 + (quad ^ sw) * 8;

  f32x4 acc[4][4];
#pragma unroll
  for (int i = 0; i < 4; i++)
#pragma unroll
    for (int j = 0; j < 4; j++) {
      f32x4 z = {0.f, 0.f, 0.f, 0.f};
      acc[i][j] = z;
    }

  for (int k0 = 0; k0 < K; k0 += 32) {
    __builtin_amdgcn_global_load_lds(
        (const __attribute__((address_space(1))) unsigned int*)(Ag0 + k0),
        (__attribute__((address_space(3))) unsigned int*)AsW0, 16, 0, 0);
    __builtin_amdgcn_global_load_lds(
        (const __attribute__((address_space(1))) unsigned int*)(Ag1 + k0),
        (__attribute__((address_space(3))) unsigned int*)AsW1, 16, 0, 0);
    __builtin_amdgcn_global_load_lds(
        (const __attribute__((address_space(1))) unsigned int*)(Bg0 + k0),
        (__attribute__((address_space(3))) unsigned int*)BsW0, 16, 0, 0);
    __builtin_amdgcn_global_load_lds(
        (const __attribute__((address_space(1))) unsigned int*)(Bg1 + k0),
        (__attribute__((address_space(3))) unsigned int*)BsW1, 16, 0, 0);
    __syncthreads();

    bf16x8 af[4], bfr[4];
#pragma unroll
    for (int i = 0; i < 4; i++) af[i] = *(const bf16x8*)(ArP + i * 16 * 32);
#pragma unroll
    for (int j = 0; j < 4; j++) bfr[j] = *(const bf16x8*)(BrP + j * 16 * 32);
#pragma unroll
    for (int i = 0; i < 4; i++)
#pragma unroll
      for (int j = 0; j < 4; j++)
        acc[i][j] = __builtin_amdgcn_mfma_f32_16x16x32_bf16(af[i], bfr[j],
                                                            acc[i][j], 0, 0, 0);
    __syncthreads();
  }

#pragma unroll
  for (int i = 0; i < 4; i++)
#pragma unroll
    for (int j = 0; j < 4; j++)
#pragma unroll
      for (int r = 0; r < 4; r++) {
        size_t row = m0 + wm + i * 16 + quad * 4 + r;
        size_t col = n0 + wn + j * 16 + l16;
        C[row * (size_t)ldc + col] = acc[i][j][r];
      }
}

extern "C" void kernel_launch(void* const* d_in, const int* in_sizes, int n_in,
                              void* d_out, int out_size, void* d_ws, size_t ws_size,
                              hipStream_t stream) {
  const float* q = (const float*)d_in[0];
  const float* k = (const float*)d_in[1];
  const float* v = (const float*)d_in[2];
  float* out = (float*)d_out;

  char* ws = (char*)d_ws;
  const size_t MB = 1024ull * 1024ull;
  unsigned short* qb     = (unsigned short*)(ws);
  unsigned short* kb     = (unsigned short*)(ws + 16 * MB);
  unsigned short* vbT    = (unsigned short*)(ws + 32 * MB);
  unsigned short* scores = (unsigned short*)(ws + 48 * MB);
  float*          scale  = (float*)(ws + 176 * MB);  // sumsq

  const int nqk = MROWS * DIN;

  // zero sumsq only (out is fully written by gemm2 plain stores)
  zero_f32_kernel<<<(MROWS / 4 + 255) / 256, 256, 0, stream>>>(scale, MROWS / 4);

  cvt_kernel<<<nqk / 1024, 256, 0, stream>>>(q, qb, nqk);
  cvt_kernel<<<nqk / 1024, 256, 0, stream>>>(k, kb, nqk);
  transpose_cvt_kernel<<<dim3(DOUT / 32, NBANK / 32), dim3(32, 8), 0, stream>>>(
      v, vbT, NBANK, DOUT);

  gemm1_kernel<<<dim3(NBANK / 256, MROWS / 128), 512, 0, stream>>>(qb, kb, scores,
                                                                   scale);

  gelu_kernel<<<4096, 256, 0, stream>>>(scores, scale);

  gemm2_kernel<<<dim3(DOUT / 128, MROWS / 128), 256, 0, stream>>>(scores, vbT, out);
}